// Round 13
// baseline (353.862 us; speedup 1.0000x reference)
//
#include <hip/hip_runtime.h>
#include <hip/hip_bf16.h>

typedef unsigned short u16;
typedef unsigned short u16x8 __attribute__((ext_vector_type(8)));
typedef short s16x8 __attribute__((ext_vector_type(8)));
typedef float f32x4 __attribute__((ext_vector_type(4)));

#define BATCH 32
#define TPAD 1024
#define TOUT 1022
#define DIM 512
#define KDIM 1536
#define NDIM 1536
#define MPAD (BATCH * TPAD)   // 32768

// ws layout (bytes)
#define XB_ELEMS  (MPAD * DIM + 1024)          // 16,778,240 bf16 (incl. tail pad)
#define XB_BYTES  (XB_ELEMS * 2)               // 33,556,480
#define WT_ELEMS  (NDIM * KDIM)                // 2,359,296
#define WT_BYTES  (WT_ELEMS * 2)               // 4,718,592
#define ACTS_OFF  (XB_BYTES + WT_BYTES)        // 38,275,072

__device__ __forceinline__ u16 f2bf(float f) {
    union { __hip_bfloat16 h; u16 u; } v;
    v.h = __float2bfloat16(f);
    return v.u;
}
__device__ __forceinline__ float bf2f(u16 u) {
    union { unsigned int i; float f; } v;
    v.i = ((unsigned int)u) << 16;
    return v.f;
}

// fast activations: v_exp + raw v_rcp (rel err ~6e-5; recurrence propagation ~1e-4 abs,
// well under the 1.45e-3 threshold margin). Saturation: exp->inf/0 gives exact 1/-1/0 limits.
__device__ __forceinline__ float fast_sigmoid(float x) {
    return __builtin_amdgcn_rcpf(1.f + __expf(-x));
}
__device__ __forceinline__ float fast_tanh(float x) {
    return 1.f - 2.f * __builtin_amdgcn_rcpf(1.f + __expf(2.f * x));
}

__device__ __forceinline__ void gload_lds16(const void* g, void* l) {
    __builtin_amdgcn_global_load_lds(
        (const __attribute__((address_space(1))) void*)g,
        (__attribute__((address_space(3))) void*)l, 16, 0, 0);
}

// compiler memory fence + HW barrier (raw s_barrier, NO vmcnt drain)
#define BARRIER() do { asm volatile("" ::: "memory"); \
                       __builtin_amdgcn_s_barrier(); \
                       asm volatile("" ::: "memory"); } while (0)

// ---------------- fused convert: x f32->bf16 (+tail pad) AND W [K][N]f32 -> [N][K]bf16 ----------------
#define CVTX_BLOCKS 8193            // ceil(XB_ELEMS/8/256)
#define CVTW_BLOCKS (48 * 48)       // (KDIM/32) * (NDIM/32)
__global__ __launch_bounds__(256) void cvt_kernel(const float* __restrict__ x,
                                                  u16* __restrict__ xb,
                                                  const float* __restrict__ w,
                                                  u16* __restrict__ wT) {
    if (blockIdx.x < CVTX_BLOCKS) {
        const int n = MPAD * DIM;         // 16,777,216
        const int ntot = XB_ELEMS;        // 16,778,240
        int i = (blockIdx.x * 256 + threadIdx.x) * 8;
        if (i >= ntot) return;
        if (i + 8 <= n) {
            const float4* p = (const float4*)(x + i);
            float4 a = p[0], b = p[1];
            u16x8 r;
            r[0] = f2bf(a.x); r[1] = f2bf(a.y); r[2] = f2bf(a.z); r[3] = f2bf(a.w);
            r[4] = f2bf(b.x); r[5] = f2bf(b.y); r[6] = f2bf(b.z); r[7] = f2bf(b.w);
            *(u16x8*)(xb + i) = r;
        } else {
            for (int q = 0; q < 8 && i + q < ntot; q++)
                xb[i + q] = (i + q < n) ? f2bf(x[i + q]) : (u16)0;
        }
    } else {
        __shared__ u16 tile[32][33];
        const int widx = blockIdx.x - CVTX_BLOCKS;
        int tx = threadIdx.x & 31, ty = threadIdx.x >> 5; // ty 0..7
        int kt = (widx % 48) * 32, jt = (widx / 48) * 32;
#pragma unroll
        for (int q = 0; q < 4; q++) {
            int k = kt + ty + q * 8;
            tile[ty + q * 8][tx] = f2bf(w[(size_t)k * NDIM + jt + tx]);
        }
        __syncthreads();
#pragma unroll
        for (int q = 0; q < 4; q++) {
            int j = jt + ty + q * 8;
            wT[(size_t)j * KDIM + kt + tx] = tile[tx][ty + q * 8];
        }
    }
}

// ---------------- GEMM: 256x256 tile, BK=64, 8 waves (2Mx4N), R5 skeleton + full loads-before-MFMA ----------------
// R5 barrier/vmcnt/stage skeleton verbatim; within every region, frag ds_reads (and
// stages) issue BEFORE the MFMA cluster so LDS-read latency/throughput overlaps the
// MFMA burst (cycle model: per CU per K-tile MFMA=2483cy, LDS=1536cy, measured total
// 4710cy => near-zero overlap in R5; setprio is side-effecting so the scheduler cannot
// do this hoist itself). R3 loads next-tile b0 before p3 consumes old b0 -> b0 ping-pong
// via 2x-unrolled kt loop.
// KEY FIX vs rounds 11/12: __launch_bounds__(512, 1). (512,2) capped the unified file at
// 256 regs/lane (compiler: 128 AGPR acc + 128 VGPR, reported VGPR_Count=128 every time);
// the reorder's longer frag live ranges (+16..32 regs) then spilled to scratch
// (FETCH +47..95MB, MfmaUtil 20-23%) — the schedule theory was never actually tested.
// (512,1) lifts the cap to 512; ~190 live regs fit; occupancy unchanged (1 block/CU,
// 2 waves/SIMD, LDS 64KB).
// Ledger (unchanged vs R5; intra-region moves cross no wait point):
//   R0 vmcnt(2)->idx4,5 landed (b1v reads);  R1 vmcnt(0)->idx6,7 landed (a2 reads);
//   R3 vmcnt(2)->idx0-3(kt+1) landed (a1/BNXT reads).
// Stage WAR: staged rows' prior reads are lgkm-consumed before the preceding region's
// MFMA issue, hence before the barrier preceding the stage. MFMA order identical to R5
// -> absmax must stay bit-identical 0.01855469 (race canary).
__global__ __launch_bounds__(512, 1) void gemm_kernel(const u16* __restrict__ xb,
                                                      const u16* __restrict__ wT,
                                                      u16* __restrict__ acts) {
    __shared__ u16 lsA[256 * 64];   // 32 KB
    __shared__ u16 lsB[256 * 64];   // 32 KB

    const int tid  = threadIdx.x;
    const int lane = tid & 63;
    const int w    = tid >> 6;       // 0..7
    const int wr   = w >> 2;         // 0..1  (M half)
    const int wc   = w & 3;          // 0..3  (N quarter)

    // XCD-chunked bijective swizzle (nwg=768 % 8 == 0): contiguous bm range per XCD.
    const int wg  = blockIdx.x;                  // 0..767
    const int gid = (wg & 7) * 96 + (wg >> 3);   // 96 per XCD
    const int bm  = gid / 6;                     // 0..127
    const int bn  = gid % 6;                     // 0..5

    const int l15  = lane & 15;
    const int kgrp = (lane >> 4) * 16;           // 0,16,32,48
    const int xorv = (lane & 7) << 4;

    // ---- stage chunk descriptors ----
    // A chunk g: rows wr*128 + g*32 + wc*8 + (lane>>3); B chunk h: rows wc*64 + h*16 + wr*8 + (lane>>3).
    const int sc = ((lane & 7) ^ (lane >> 3)) << 4;   // pre-swizzled within-row byte
    const char* gsrc[8];
    char* ldst[8];
    {
        const char* gA = (const char*)xb;
        const char* gB = (const char*)wT;
#pragma unroll
        for (int g = 0; g < 4; g++) {
            int r0 = wr * 128 + g * 32 + wc * 8;
            int idx = (g < 2) ? g : (4 + g);          // 0,1,6,7
            gsrc[idx] = gA + (size_t)(bm * 256 + r0 + (lane >> 3)) * 1024 + sc;
            ldst[idx] = (char*)lsA + r0 * 128;
        }
#pragma unroll
        for (int h = 0; h < 4; h++) {
            int r0 = wc * 64 + h * 16 + wr * 8;
            int idx = 2 + h;                          // 2,3,4,5
            gsrc[idx] = gB + (size_t)(bn * 256 + r0 + (lane >> 3)) * 3072 + sc;
            ldst[idx] = (char*)lsB + r0 * 128;
        }
    }

    f32x4 acc[8][4] = {};
    s16x8 a1[4][2];       // A frags, qm0 slot
    s16x8 a2[4][2];       // A frags, qm1 slot
    s16x8 b0A[2][2];      // B frags qn0, ping
    s16x8 b0B[2][2];      // B frags qn0, pong
    s16x8 b1v[2][2];      // B frags, qn1

#define STAGE(IDX) gload_lds16(gsrc[IDX] + koff, ldst[IDX])

#define LOAD_A(DST, QM) \
    _Pragma("unroll") for (int ii = 0; ii < 4; ii++) \
    _Pragma("unroll") for (int kk = 0; kk < 2; kk++) { \
        int row = wr * 128 + (QM) * 64 + ii * 16 + l15; \
        int byte = (row * 128 + kk * 64 + kgrp) ^ xorv; \
        DST[ii][kk] = *(const s16x8*)((const char*)lsA + byte); }

#define LOAD_B(DST, QN) \
    _Pragma("unroll") for (int jj = 0; jj < 2; jj++) \
    _Pragma("unroll") for (int kk = 0; kk < 2; kk++) { \
        int row = wc * 64 + (QN) * 32 + jj * 16 + l15; \
        int byte = (row * 128 + kk * 64 + kgrp) ^ xorv; \
        DST[jj][kk] = *(const s16x8*)((const char*)lsB + byte); }

#define MFMA_QUAD(ASET, BSET, QM, QN) \
    __builtin_amdgcn_s_setprio(1); \
    _Pragma("unroll") for (int ii = 0; ii < 4; ii++) \
    _Pragma("unroll") for (int jj = 0; jj < 2; jj++) \
    _Pragma("unroll") for (int kk = 0; kk < 2; kk++) \
        acc[(QM)*4+ii][(QN)*2+jj] = __builtin_amdgcn_mfma_f32_16x16x32_bf16( \
            ASET[ii][kk], BSET[jj][kk], acc[(QM)*4+ii][(QN)*2+jj], 0, 0, 0); \
    __builtin_amdgcn_s_setprio(0);

// one K-tile iteration; BCUR = b0 set consumed this tile, BNXT = set loaded for next tile
#define ITER(KT, BCUR, BNXT) { \
        const int knext = ((KT) + 1 == NT) ? 0 : ((KT) + 1); \
        const size_t koff = (size_t)knext * 128; \
        /* R0: cert idx4,5; reads for p1 BEFORE MFMA p0 */ \
        asm volatile("s_waitcnt vmcnt(2)" ::: "memory"); \
        BARRIER(); \
        LOAD_B(b1v, 1) \
        MFMA_QUAD(a1, BCUR, 0, 0) \
        /* R1: cert idx6,7; reads for p2; stage idx0-3; MFMA p1 */ \
        asm volatile("s_waitcnt vmcnt(0)" ::: "memory"); \
        BARRIER(); \
        LOAD_A(a2, 1) \
        STAGE(0); STAGE(1); STAGE(2); STAGE(3); \
        MFMA_QUAD(a1, b1v, 0, 1) \
        /* R2: stage idx4,5; MFMA p2 */ \
        BARRIER(); \
        STAGE(4); STAGE(5); \
        MFMA_QUAD(a2, b1v, 1, 1) \
        /* R3: cert idx0-3(next); reads next-tile p0 frags; stage idx6,7; MFMA p3 */ \
        asm volatile("s_waitcnt vmcnt(2)" ::: "memory"); \
        BARRIER(); \
        LOAD_A(a1, 0) \
        LOAD_B(BNXT, 0) \
        STAGE(6); STAGE(7); \
        MFMA_QUAD(a2, BCUR, 1, 0) \
    }

    // ---- prologue: stage K-tile 0; certify idx0-3; preload p0 frags ----
    {
        size_t koff = 0;
        STAGE(0); STAGE(1); STAGE(2); STAGE(3);
        STAGE(4); STAGE(5); STAGE(6); STAGE(7);
    }
    asm volatile("s_waitcnt vmcnt(4)" ::: "memory");
    BARRIER();
    LOAD_A(a1, 0)
    LOAD_B(b0A, 0)

    const int NT = KDIM / 64;   // 24 (even)
    for (int kt = 0; kt < NT; kt += 2) {
        ITER(kt, b0A, b0B)
        ITER(kt + 1, b0B, b0A)
    }

    asm volatile("s_waitcnt vmcnt(0)" ::: "memory");  // drain wrap stages before epilogue

#undef ITER
#undef STAGE
#undef LOAD_A
#undef LOAD_B
#undef MFMA_QUAD

    // ---- epilogue: C/D layout col = lane&15, row = (lane>>4)*4 + reg ----
    const int m0 = bm * 256 + wr * 128 + ((lane >> 4) << 2);
    const int n0 = bn * 256 + wc * 64 + (lane & 15);
#pragma unroll
    for (int i = 0; i < 8; i++)
#pragma unroll
        for (int j = 0; j < 4; j++)
#pragma unroll
            for (int r = 0; r < 4; r++) {
                int m = m0 + i * 16 + r;
                int n = n0 + j * 16;
                acts[(size_t)m * NDIM + n] = f2bf(acc[i][j][r]);
            }
}

// ---------------- chunked parallel scan ----------------
// One block per (b, 64-u group): 1024 threads = 16 waves. Wave w owns t-chunk
// [w*64, min((w+1)*64, 1022)). Affine recurrence composes: c_end = A*c_in + B.
// Pass 1 computes (A,B)/lane; LDS combine gives each wave its exact c_in;
// pass 2 re-reads z/f/o (L2/L3-hot) and replays, writing h = o*c.
// Fast activations (exp+rcp) — round-10: −19us vs libm tanhf/divides.
#define CHUNK 64
__global__ __launch_bounds__(1024) void scan_kernel(const u16* __restrict__ acts,
                                                    float* __restrict__ out) {
    __shared__ float sA[16][64];
    __shared__ float sB[16][64];
    const int lane = threadIdx.x & 63;
    const int w = threadIdx.x >> 6;          // 0..15
    const int b = blockIdx.x >> 3;           // 0..31
    const int u = ((blockIdx.x & 7) << 6) + lane;  // 0..511
    const u16* base = acts + (size_t)b * TPAD * NDIM;
    const int t0 = w * CHUNK;
    const int t1 = (t0 + CHUNK < TOUT) ? (t0 + CHUNK) : TOUT;

    // ---- pass 1: chunk summary (A = prod f, B = chunk-local c) ----
    float A = 1.f, Bc = 0.f;
    int t = t0;
    for (; t + 8 <= t1; t += 8) {
        u16 zv[8], fv[8];
#pragma unroll
        for (int q = 0; q < 8; q++) {
            const u16* r = base + (size_t)(t + q) * NDIM;
            zv[q] = r[u]; fv[q] = r[512 + u];
        }
#pragma unroll
        for (int q = 0; q < 8; q++) {
            float z = fast_tanh(bf2f(zv[q]));
            float f = fast_sigmoid(bf2f(fv[q]));
            Bc = f * Bc + (1.f - f) * z;
            A *= f;
        }
    }
    for (; t < t1; t++) {
        const u16* r = base + (size_t)t * NDIM;
        float z = fast_tanh(bf2f(r[u]));
        float f = fast_sigmoid(bf2f(r[512 + u]));
        Bc = f * Bc + (1.f - f) * z;
        A *= f;
    }
    sA[w][lane] = A; sB[w][lane] = Bc;
    __syncthreads();

    // ---- combine: c_in for this wave's chunk ----
    float c = 0.f;
    for (int w2 = 0; w2 < w; w2++)
        c = sA[w2][lane] * c + sB[w2][lane];

    // ---- pass 2: replay with correct c_in, write h = o*c ----
    float* ob = out + (size_t)b * (TOUT * DIM) + u;
    t = t0;
    for (; t + 8 <= t1; t += 8) {
        u16 zv[8], fv[8], ov[8];
#pragma unroll
        for (int q = 0; q < 8; q++) {
            const u16* r = base + (size_t)(t + q) * NDIM;
            zv[q] = r[u]; fv[q] = r[512 + u]; ov[q] = r[1024 + u];
        }
#pragma unroll
        for (int q = 0; q < 8; q++) {
            float z = fast_tanh(bf2f(zv[q]));
            float f = fast_sigmoid(bf2f(fv[q]));
            float o = fast_sigmoid(bf2f(ov[q]));
            c = f * c + (1.f - f) * z;
            ob[(size_t)(t + q) * DIM] = o * c;
        }
    }
    for (; t < t1; t++) {
        const u16* r = base + (size_t)t * NDIM;
        float z = fast_tanh(bf2f(r[u]));
        float f = fast_sigmoid(bf2f(r[512 + u]));
        float o = fast_sigmoid(bf2f(r[1024 + u]));
        c = f * c + (1.f - f) * z;
        ob[(size_t)t * DIM] = o * c;
    }
}

extern "C" void kernel_launch(void* const* d_in, const int* in_sizes, int n_in,
                              void* d_out, int out_size, void* d_ws, size_t ws_size,
                              hipStream_t stream) {
    const float* x = (const float*)d_in[0];   // (32,1024,512) f32
    const float* w = (const float*)d_in[1];   // (3,512,1536) f32
    float* out = (float*)d_out;               // (32,1022,512) f32
    char* ws = (char*)d_ws;

    u16* xb   = (u16*)ws;                     // bf16 x (+pad)
    u16* wT   = (u16*)(ws + XB_BYTES);        // bf16 W^T [N][K]
    u16* acts = (u16*)(ws + ACTS_OFF);        // bf16 pre-activations [32768][1536]

    cvt_kernel<<<dim3(CVTX_BLOCKS + CVTW_BLOCKS), dim3(256), 0, stream>>>(x, xb, w, wT);
    gemm_kernel<<<dim3(768), dim3(512), 0, stream>>>(xb, wT, acts);
    scan_kernel<<<dim3(256), dim3(1024), 0, stream>>>(acts, out);
}

// Round 14
// 197.507 us; speedup vs baseline: 1.7916x; 1.7916x over previous
//
#include <hip/hip_runtime.h>
#include <hip/hip_bf16.h>

typedef unsigned short u16;
typedef unsigned short u16x8 __attribute__((ext_vector_type(8)));
typedef short s16x8 __attribute__((ext_vector_type(8)));
typedef float f32x4 __attribute__((ext_vector_type(4)));

#define BATCH 32
#define TPAD 1024
#define TOUT 1022
#define DIM 512
#define KDIM 1536
#define NDIM 1536
#define MPAD (BATCH * TPAD)   // 32768

// ws layout (bytes)
#define XB_ELEMS  (MPAD * DIM + 1024)          // 16,778,240 bf16 (incl. tail pad)
#define XB_BYTES  (XB_ELEMS * 2)               // 33,556,480
#define WT_ELEMS  (NDIM * KDIM)                // 2,359,296
#define WT_BYTES  (WT_ELEMS * 2)               // 4,718,592
#define ACTS_OFF  (XB_BYTES + WT_BYTES)        // 38,275,072

__device__ __forceinline__ u16 f2bf(float f) {
    union { __hip_bfloat16 h; u16 u; } v;
    v.h = __float2bfloat16(f);
    return v.u;
}
__device__ __forceinline__ float bf2f(u16 u) {
    union { unsigned int i; float f; } v;
    v.i = ((unsigned int)u) << 16;
    return v.f;
}

// fast activations: v_exp + raw v_rcp (rel err ~6e-5; recurrence propagation ~1e-4 abs,
// well under the 1.45e-3 threshold margin). Saturation: exp->inf/0 gives exact 1/-1/0 limits.
__device__ __forceinline__ float fast_sigmoid(float x) {
    return __builtin_amdgcn_rcpf(1.f + __expf(-x));
}
__device__ __forceinline__ float fast_tanh(float x) {
    return 1.f - 2.f * __builtin_amdgcn_rcpf(1.f + __expf(2.f * x));
}

__device__ __forceinline__ void gload_lds16(const void* g, void* l) {
    __builtin_amdgcn_global_load_lds(
        (const __attribute__((address_space(1))) void*)g,
        (__attribute__((address_space(3))) void*)l, 16, 0, 0);
}

// compiler memory fence + HW barrier (raw s_barrier, NO vmcnt drain)
#define BARRIER() do { asm volatile("" ::: "memory"); \
                       __builtin_amdgcn_s_barrier(); \
                       asm volatile("" ::: "memory"); } while (0)

// ---------------- fused convert: x f32->bf16 (+tail pad) AND W [K][N]f32 -> [N][K]bf16 ----------------
#define CVTX_BLOCKS 8193            // ceil(XB_ELEMS/8/256)
#define CVTW_BLOCKS (48 * 48)       // (KDIM/32) * (NDIM/32)
__global__ __launch_bounds__(256) void cvt_kernel(const float* __restrict__ x,
                                                  u16* __restrict__ xb,
                                                  const float* __restrict__ w,
                                                  u16* __restrict__ wT) {
    if (blockIdx.x < CVTX_BLOCKS) {
        const int n = MPAD * DIM;         // 16,777,216
        const int ntot = XB_ELEMS;        // 16,778,240
        int i = (blockIdx.x * 256 + threadIdx.x) * 8;
        if (i >= ntot) return;
        if (i + 8 <= n) {
            const float4* p = (const float4*)(x + i);
            float4 a = p[0], b = p[1];
            u16x8 r;
            r[0] = f2bf(a.x); r[1] = f2bf(a.y); r[2] = f2bf(a.z); r[3] = f2bf(a.w);
            r[4] = f2bf(b.x); r[5] = f2bf(b.y); r[6] = f2bf(b.z); r[7] = f2bf(b.w);
            *(u16x8*)(xb + i) = r;
        } else {
            for (int q = 0; q < 8 && i + q < ntot; q++)
                xb[i + q] = (i + q < n) ? f2bf(x[i + q]) : (u16)0;
        }
    } else {
        __shared__ u16 tile[32][33];
        const int widx = blockIdx.x - CVTX_BLOCKS;
        int tx = threadIdx.x & 31, ty = threadIdx.x >> 5; // ty 0..7
        int kt = (widx % 48) * 32, jt = (widx / 48) * 32;
#pragma unroll
        for (int q = 0; q < 4; q++) {
            int k = kt + ty + q * 8;
            tile[ty + q * 8][tx] = f2bf(w[(size_t)k * NDIM + jt + tx]);
        }
        __syncthreads();
#pragma unroll
        for (int q = 0; q < 4; q++) {
            int j = jt + ty + q * 8;
            wT[(size_t)j * KDIM + kt + tx] = tile[tx][ty + q * 8];
        }
    }
}

// ---------------- GEMM: 256x256 tile, BK=64, 8 waves (2Mx4N), R5 pipelined phased schedule ----------------
// CONVERGED (round-5 schedule, 141.3us, MfmaUtil 47.4, conflicts 0, no spill). Beat all 8
// mutations: (512,4) occupancy (R6: forced 64 VGPR, spill), dbuf deep pipeline (R7),
// m201-style 8-barrier lockstep (R8), 32x32x16 shape (R9: 4-way bank conflict), and
// loads-before-MFMA reorder x3 (R11-R13: allocator pins 128 arch VGPRs for 8-wave blocks
// with 128-AGPR acc regardless of launch_bounds -> any longer frag live range spills to
// scratch; the overlap transform needs inline-asm ds_read with pinned regs = out of scope).
// In-place single-buffered LDS (A 32KB + B 32KB). Region R_p per K-tile:
//   { vmcnt(cert); BARRIER; MFMA(phase p) on frags loaded in R_{p-1}; ds-load frags for
//     phase p+1; global_load_lds stages per schedule }
// Phases: p0=(qm0,qn0) p1=(qm0,qn1) p2=(qm1,qn1) p3=(qm1,qn0).
// Stage idx: 0=Ag0 1=Ag1 2=Bh0 3=Bh1 4=Bh2 5=Bh3 6=Ag2 7=Ag3; stages R1:0-3, R2:4,5, R3:6,7.
// Cert ledger (per-wave, SPMD-symmetric; vmcnt BEFORE barrier): R0 vmcnt(2)->idx4,5;
// R1 vmcnt(0)->idx6,7; R3 vmcnt(2)->idx0-3(kt+1). Every stage lands >=1 barrier after its
// rows' last read-consumption. b(qn0) frags live in regs R3->R3. XOR swizzle (row&7)<<4
// via pre-swizzled global source + swizzled ds_read addr (T2). setprio (T5).
__global__ __launch_bounds__(512, 2) void gemm_kernel(const u16* __restrict__ xb,
                                                      const u16* __restrict__ wT,
                                                      u16* __restrict__ acts) {
    __shared__ u16 lsA[256 * 64];   // 32 KB
    __shared__ u16 lsB[256 * 64];   // 32 KB

    const int tid  = threadIdx.x;
    const int lane = tid & 63;
    const int w    = tid >> 6;       // 0..7
    const int wr   = w >> 2;         // 0..1  (M half)
    const int wc   = w & 3;          // 0..3  (N quarter)

    // XCD-chunked bijective swizzle (nwg=768 % 8 == 0): contiguous bm range per XCD.
    const int wg  = blockIdx.x;                  // 0..767
    const int gid = (wg & 7) * 96 + (wg >> 3);   // 96 per XCD
    const int bm  = gid / 6;                     // 0..127
    const int bn  = gid % 6;                     // 0..5

    const int l15  = lane & 15;
    const int kgrp = (lane >> 4) * 16;           // 0,16,32,48
    const int xorv = (lane & 7) << 4;

    // ---- stage chunk descriptors ----
    // A chunk g: rows wr*128 + g*32 + wc*8 + (lane>>3); B chunk h: rows wc*64 + h*16 + wr*8 + (lane>>3).
    const int sc = ((lane & 7) ^ (lane >> 3)) << 4;   // pre-swizzled within-row byte
    const char* gsrc[8];
    char* ldst[8];
    {
        const char* gA = (const char*)xb;
        const char* gB = (const char*)wT;
#pragma unroll
        for (int g = 0; g < 4; g++) {
            int r0 = wr * 128 + g * 32 + wc * 8;
            int idx = (g < 2) ? g : (4 + g);          // 0,1,6,7
            gsrc[idx] = gA + (size_t)(bm * 256 + r0 + (lane >> 3)) * 1024 + sc;
            ldst[idx] = (char*)lsA + r0 * 128;
        }
#pragma unroll
        for (int h = 0; h < 4; h++) {
            int r0 = wc * 64 + h * 16 + wr * 8;
            int idx = 2 + h;                          // 2,3,4,5
            gsrc[idx] = gB + (size_t)(bn * 256 + r0 + (lane >> 3)) * 3072 + sc;
            ldst[idx] = (char*)lsB + r0 * 128;
        }
    }

    f32x4 acc[8][4] = {};
    s16x8 a1[4][2];       // A frags, qm0 slot
    s16x8 a2[4][2];       // A frags, qm1 slot
    s16x8 b0[2][2];       // B frags, qn0 (live full K-tile)
    s16x8 b1v[2][2];      // B frags, qn1

#define STAGE(IDX) gload_lds16(gsrc[IDX] + koff, ldst[IDX])

#define LOAD_A(DST, QM) \
    _Pragma("unroll") for (int ii = 0; ii < 4; ii++) \
    _Pragma("unroll") for (int kk = 0; kk < 2; kk++) { \
        int row = wr * 128 + (QM) * 64 + ii * 16 + l15; \
        int byte = (row * 128 + kk * 64 + kgrp) ^ xorv; \
        DST[ii][kk] = *(const s16x8*)((const char*)lsA + byte); }

#define LOAD_B(DST, QN) \
    _Pragma("unroll") for (int jj = 0; jj < 2; jj++) \
    _Pragma("unroll") for (int kk = 0; kk < 2; kk++) { \
        int row = wc * 64 + (QN) * 32 + jj * 16 + l15; \
        int byte = (row * 128 + kk * 64 + kgrp) ^ xorv; \
        DST[jj][kk] = *(const s16x8*)((const char*)lsB + byte); }

#define MFMA_QUAD(ASET, BSET, QM, QN) \
    __builtin_amdgcn_s_setprio(1); \
    _Pragma("unroll") for (int ii = 0; ii < 4; ii++) \
    _Pragma("unroll") for (int jj = 0; jj < 2; jj++) \
    _Pragma("unroll") for (int kk = 0; kk < 2; kk++) \
        acc[(QM)*4+ii][(QN)*2+jj] = __builtin_amdgcn_mfma_f32_16x16x32_bf16( \
            ASET[ii][kk], BSET[jj][kk], acc[(QM)*4+ii][(QN)*2+jj], 0, 0, 0); \
    __builtin_amdgcn_s_setprio(0);

    // ---- prologue: stage K-tile 0; certify idx0-3; preload p0 frags ----
    {
        size_t koff = 0;
        STAGE(0); STAGE(1); STAGE(2); STAGE(3);
        STAGE(4); STAGE(5); STAGE(6); STAGE(7);
    }
    asm volatile("s_waitcnt vmcnt(4)" ::: "memory");
    BARRIER();
    LOAD_A(a1, 0)
    LOAD_B(b0, 0)

    const int NT = KDIM / 64;   // 24
    for (int kt = 0; kt < NT; kt++) {
        const int knext = (kt + 1 == NT) ? 0 : (kt + 1);  // wrap: tail stages/loads harmless
        const size_t koff = (size_t)knext * 128;

        // ---- R0: MFMA p0 (a1,b0); hoist loads for p1 (b qn1 = idx4,5 rows) ----
        asm volatile("s_waitcnt vmcnt(2)" ::: "memory");
        BARRIER();
        MFMA_QUAD(a1, b0, 0, 0)
        LOAD_B(b1v, 1)

        // ---- R1: MFMA p1 (a1,b1v); hoist loads for p2 (a qm1 = idx6,7 rows); stage idx0-3 ----
        asm volatile("s_waitcnt vmcnt(0)" ::: "memory");
        BARRIER();
        MFMA_QUAD(a1, b1v, 0, 1)
        LOAD_A(a2, 1)
        STAGE(0); STAGE(1); STAGE(2); STAGE(3);

        // ---- R2 (no vmcnt): MFMA p2 (a2,b1v); stage idx4,5 ----
        BARRIER();
        MFMA_QUAD(a2, b1v, 1, 1)
        STAGE(4); STAGE(5);

        // ---- R3: MFMA p3 (a2,b0); loads for next tile's p0 (idx0-3(kt+1) rows); stage idx6,7 ----
        asm volatile("s_waitcnt vmcnt(2)" ::: "memory");
        BARRIER();
        MFMA_QUAD(a2, b0, 1, 0)
        LOAD_A(a1, 0)
        LOAD_B(b0, 0)
        STAGE(6); STAGE(7);
    }

    asm volatile("s_waitcnt vmcnt(0)" ::: "memory");  // drain wrap stages before epilogue

#undef STAGE
#undef LOAD_A
#undef LOAD_B
#undef MFMA_QUAD

    // ---- epilogue: C/D layout col = lane&15, row = (lane>>4)*4 + reg ----
    const int m0 = bm * 256 + wr * 128 + ((lane >> 4) << 2);
    const int n0 = bn * 256 + wc * 64 + (lane & 15);
#pragma unroll
    for (int i = 0; i < 8; i++)
#pragma unroll
        for (int j = 0; j < 4; j++)
#pragma unroll
            for (int r = 0; r < 4; r++) {
                int m = m0 + i * 16 + r;
                int n = n0 + j * 16;
                acts[(size_t)m * NDIM + n] = f2bf(acc[i][j][r]);
            }
}

// ---------------- chunked parallel scan ----------------
// One block per (b, 64-u group): 1024 threads = 16 waves. Wave w owns t-chunk
// [w*64, min((w+1)*64, 1022)). Affine recurrence composes: c_end = A*c_in + B.
// Pass 1 computes (A,B)/lane; LDS combine gives each wave its exact c_in;
// pass 2 re-reads z/f/o (L2/L3-hot) and replays, writing h = o*c.
// Fast activations (exp+rcp) — round-10: −19us vs libm tanhf/divides.
// Runs at ~5.9 TB/s effective (234MB HBM-min traffic) — at the BW ceiling.
#define CHUNK 64
__global__ __launch_bounds__(1024) void scan_kernel(const u16* __restrict__ acts,
                                                    float* __restrict__ out) {
    __shared__ float sA[16][64];
    __shared__ float sB[16][64];
    const int lane = threadIdx.x & 63;
    const int w = threadIdx.x >> 6;          // 0..15
    const int b = blockIdx.x >> 3;           // 0..31
    const int u = ((blockIdx.x & 7) << 6) + lane;  // 0..511
    const u16* base = acts + (size_t)b * TPAD * NDIM;
    const int t0 = w * CHUNK;
    const int t1 = (t0 + CHUNK < TOUT) ? (t0 + CHUNK) : TOUT;

    // ---- pass 1: chunk summary (A = prod f, B = chunk-local c) ----
    float A = 1.f, Bc = 0.f;
    int t = t0;
    for (; t + 8 <= t1; t += 8) {
        u16 zv[8], fv[8];
#pragma unroll
        for (int q = 0; q < 8; q++) {
            const u16* r = base + (size_t)(t + q) * NDIM;
            zv[q] = r[u]; fv[q] = r[512 + u];
        }
#pragma unroll
        for (int q = 0; q < 8; q++) {
            float z = fast_tanh(bf2f(zv[q]));
            float f = fast_sigmoid(bf2f(fv[q]));
            Bc = f * Bc + (1.f - f) * z;
            A *= f;
        }
    }
    for (; t < t1; t++) {
        const u16* r = base + (size_t)t * NDIM;
        float z = fast_tanh(bf2f(r[u]));
        float f = fast_sigmoid(bf2f(r[512 + u]));
        Bc = f * Bc + (1.f - f) * z;
        A *= f;
    }
    sA[w][lane] = A; sB[w][lane] = Bc;
    __syncthreads();

    // ---- combine: c_in for this wave's chunk ----
    float c = 0.f;
    for (int w2 = 0; w2 < w; w2++)
        c = sA[w2][lane] * c + sB[w2][lane];

    // ---- pass 2: replay with correct c_in, write h = o*c ----
    float* ob = out + (size_t)b * (TOUT * DIM) + u;
    t = t0;
    for (; t + 8 <= t1; t += 8) {
        u16 zv[8], fv[8], ov[8];
#pragma unroll
        for (int q = 0; q < 8; q++) {
            const u16* r = base + (size_t)(t + q) * NDIM;
            zv[q] = r[u]; fv[q] = r[512 + u]; ov[q] = r[1024 + u];
        }
#pragma unroll
        for (int q = 0; q < 8; q++) {
            float z = fast_tanh(bf2f(zv[q]));
            float f = fast_sigmoid(bf2f(fv[q]));
            float o = fast_sigmoid(bf2f(ov[q]));
            c = f * c + (1.f - f) * z;
            ob[(size_t)(t + q) * DIM] = o * c;
        }
    }
    for (; t < t1; t++) {
        const u16* r = base + (size_t)t * NDIM;
        float z = fast_tanh(bf2f(r[u]));
        float f = fast_sigmoid(bf2f(r[512 + u]));
        float o = fast_sigmoid(bf2f(r[1024 + u]));
        c = f * c + (1.f - f) * z;
        ob[(size_t)t * DIM] = o * c;
    }
}

extern "C" void kernel_launch(void* const* d_in, const int* in_sizes, int n_in,
                              void* d_out, int out_size, void* d_ws, size_t ws_size,
                              hipStream_t stream) {
    const float* x = (const float*)d_in[0];   // (32,1024,512) f32
    const float* w = (const float*)d_in[1];   // (3,512,1536) f32
    float* out = (float*)d_out;               // (32,1022,512) f32
    char* ws = (char*)d_ws;

    u16* xb   = (u16*)ws;                     // bf16 x (+pad)
    u16* wT   = (u16*)(ws + XB_BYTES);        // bf16 W^T [N][K]
    u16* acts = (u16*)(ws + ACTS_OFF);        // bf16 pre-activations [32768][1536]

    cvt_kernel<<<dim3(CVTX_BLOCKS + CVTW_BLOCKS), dim3(256), 0, stream>>>(x, xb, w, wT);
    gemm_kernel<<<dim3(768), dim3(512), 0, stream>>>(xb, wT, acts);
    scan_kernel<<<dim3(256), dim3(1024), 0, stream>>>(acts, out);
}